// Round 7
// baseline (259.756 us; speedup 1.0000x reference)
//
#include <hip/hip_runtime.h>

#define NC_  256
#define CN_  256
#define K_   16
#define DN_  64
#define G_   8
#define HM_  128
#define F3_  192

typedef unsigned short u16;
typedef short v8s __attribute__((ext_vector_type(8)));
typedef float v4f __attribute__((ext_vector_type(4)));

// ---- kernels ---------------------------------------------------------------
// cvt_w   : f32->bf16 weight tables into d_ws (1 MB)
// gth     : gather agg[b,n,c,:] = sum_k w*h[nbr]  -> f32 into oM region (same
//           indices msg will later occupy; each (cell,chunk) slot is consumed
//           as agg by exactly the block that overwrites it with msg)
// mg_main : 1-wave blocks (64 thr), 32 rows each, no barriers; MLP chain via
//           MFMA with LDS only for the mh/am transposes (13.6 KB static)
// mg_mod  : modulation MLP from pooled partials
//
// d_ws: bf16 weights @0 (1 MB), partial f32 [4096][128] @ byte 1048576 (2 MB)

__device__ __forceinline__ u16 f2b(float f) {
    unsigned v; __builtin_memcpy(&v, &f, 4);
    v = v + 0x7fffu + ((v >> 16) & 1u);   // RNE
    return (u16)(v >> 16);
}
__device__ __forceinline__ v8s cvt8(const float* p) {
    float4 a = *(const float4*)p, b = *(const float4*)(p + 4);
    v8s r;
    r[0] = (short)f2b(a.x); r[1] = (short)f2b(a.y); r[2] = (short)f2b(a.z); r[3] = (short)f2b(a.w);
    r[4] = (short)f2b(b.x); r[5] = (short)f2b(b.y); r[6] = (short)f2b(b.z); r[7] = (short)f2b(b.w);
    return r;
}
__device__ __forceinline__ float gelu_t(float x) {
    // jax.nn.gelu approximate=True: x*sigmoid(2*k0*x*(1+k1*x^2))
    float u = x * x;
    float t = 1.5957691216057308f * x * __builtin_fmaf(0.044715f, u, 1.0f);
    float e = __expf(-t);
    return x * __builtin_amdgcn_rcpf(1.0f + e);
}

__global__ __launch_bounds__(256) void cvt_w(
    const float* __restrict__ mw1, const float* __restrict__ mw2,
    const float* __restrict__ sw1, const float* __restrict__ sw2,
    u16* __restrict__ dst)
{
    int e = (blockIdx.x * 256 + threadIdx.x) * 4;   // 131072 threads * 4 = 524288
    const float* s; int off;
    if      (e < 196608) { s = mw1; off = e; }
    else if (e < 262144) { s = mw2; off = e - 196608; }
    else if (e < 458752) { s = sw1; off = e - 262144; }
    else                 { s = sw2; off = e - 458752; }
    float4 v = *(const float4*)(s + off);
    ushort4 o4;
    o4.x = f2b(v.x); o4.y = f2b(v.y); o4.z = f2b(v.z); o4.w = f2b(v.w);
    *(ushort4*)(dst + e) = o4;
}

// ---- gather: pure streaming, no LDS, no barriers ---------------------------
// block p -> (bnc = (p&7)*64 + (p>>6), chunk = (p>>3)&7): XCD x owns cells
// [x*64, x*64+64) so a cell's h stays in one XCD's L2.
__global__ __launch_bounds__(256) void gth(
    const float* __restrict__ h, const float* __restrict__ wconn,
    const int* __restrict__ conn, float* __restrict__ outf)
{
    const int p     = blockIdx.x;                 // 0..4095
    const int bnc   = (p & 7) * 64 + (p >> 6);
    const int chunk = (p >> 3) & 7;
    const int wave  = threadIdx.x >> 6, lane = threadIdx.x & 63;
    const int r0    = chunk * 32 + wave * 8;      // 8 rows per wave
    const int n     = bnc & 255;
    const size_t hb = (size_t)bnc * 16384;
    const float* __restrict__ hp = h + hb;
    float* aggo = outf + (size_t)8388608 + hb;    // oM region, f32, msg indices
    const int*   __restrict__ cp = conn  + n * 4096 + r0 * 16;
    const float* __restrict__ wp = wconn + (size_t)bnc * 4096 + (size_t)r0 * 16;
    int   ivA = cp[lane],      ivB = cp[64 + lane];   // rows r0..r0+3 / +4..+7
    float wvA = wp[lane],      wvB = wp[64 + lane];
#pragma unroll
    for (int i = 0; i < 8; ++i) {
        int   iv = (i < 4) ? ivA : ivB;
        float wv = (i < 4) ? wvA : wvB;
        float a0 = 0.0f, a1 = 0.0f;
#pragma unroll
        for (int k = 0; k < 16; k += 2) {
            const int l0 = (i & 3) * 16 + k;
            int   i0 = __builtin_amdgcn_readlane(iv, l0);
            int   i1 = __builtin_amdgcn_readlane(iv, l0 + 1);
            float w0 = __int_as_float(__builtin_amdgcn_readlane(__float_as_int(wv), l0));
            float w1 = __int_as_float(__builtin_amdgcn_readlane(__float_as_int(wv), l0 + 1));
            a0 = __builtin_fmaf(w0, hp[i0 * 64 + lane], a0);   // coalesced 256B
            a1 = __builtin_fmaf(w1, hp[i1 * 64 + lane], a1);
        }
        aggo[(size_t)(r0 + i) * 64 + lane] = a0 + a1;
    }
}

// ---- main MLP chain: 1 wave / 32 rows, no barriers -------------------------
__global__ __launch_bounds__(64, 3) void mg_main(
    const float* __restrict__ h,    const float* __restrict__ ctx,
    const float* __restrict__ nid,
    const u16* __restrict__ mw1b,   const float* __restrict__ mb1,
    const u16* __restrict__ mw2b,   const float* __restrict__ mb2,
    const u16* __restrict__ sw1b,   const float* __restrict__ sb1,
    const u16* __restrict__ sw2b,   const float* __restrict__ sb2,
    const int* __restrict__ c2g,
    float* __restrict__ outf,       float* __restrict__ partial)
{
    const int p     = blockIdx.x;                 // 0..4095, same map as gth
    const int bnc   = (p & 7) * 64 + (p >> 6);
    const int chunk = (p >> 3) & 7;
    const int r0    = chunk * 32;
    const int n     = bnc & 255;
    const int g     = c2g[n];
    const int lane  = threadIdx.x;
    const int q     = lane >> 4, ln = lane & 15;

    __shared__ u16 mh[32 * 138];   // 8832 B  (stride 138 -> banks spread)
    __shared__ u16 am[32 * 74];    // 4736 B

    const size_t hbase = (size_t)bnc * 16384;
    const size_t nbase = (size_t)n   * 16384;
    float* oH = outf + hbase;
    float* oM = outf + (size_t)8388608 + hbase;   // holds agg (f32) until m2
    const size_t pbase = (size_t)(bnc * 8 + chunk) * 128;

    // ---------------- A-fragments straight from global (L2-hot) --------------
    v8s hfr[2][2], gfr[2][2], nfr[2][2];
#pragma unroll
    for (int mi = 0; mi < 2; ++mi) {
        int c = r0 + mi * 16 + ln;
        hfr[mi][0] = cvt8(h   + hbase + (size_t)c * 64 +  0 + q * 8);
        hfr[mi][1] = cvt8(h   + hbase + (size_t)c * 64 + 32 + q * 8);
        gfr[mi][0] = cvt8(oM  + (size_t)c * 64 +  0 + q * 8);        // agg
        gfr[mi][1] = cvt8(oM  + (size_t)c * 64 + 32 + q * 8);
        nfr[mi][0] = cvt8(nid + nbase + (size_t)c * 64 +  0 + q * 8);
        nfr[mi][1] = cvt8(nid + nbase + (size_t)c * 64 + 32 + q * 8);
    }

    // ---------------- m1: mh = gelu([h|agg|nid] @ mw1^T + mb1) ---------------
    {
        v8s afr0[6] = {hfr[0][0], hfr[0][1], gfr[0][0], gfr[0][1], nfr[0][0], nfr[0][1]};
        v8s afr1[6] = {hfr[1][0], hfr[1][1], gfr[1][0], gfr[1][1], nfr[1][0], nfr[1][1]};
        float b1v[8];
#pragma unroll
        for (int nt = 0; nt < 8; ++nt) b1v[nt] = mb1[g * HM_ + nt * 16 + ln];
        const u16* w1g = mw1b + (size_t)g * HM_ * F3_;
#pragma unroll
        for (int nt = 0; nt < 8; ++nt) {
            v4f acc0 = {0,0,0,0}, acc1 = {0,0,0,0};
#pragma unroll
            for (int ks = 0; ks < 6; ++ks) {
                v8s bf = *(const v8s*)(w1g + (nt * 16 + ln) * F3_ + ks * 32 + q * 8);
                acc0 = __builtin_amdgcn_mfma_f32_16x16x32_bf16(afr0[ks], bf, acc0, 0, 0, 0);
                acc1 = __builtin_amdgcn_mfma_f32_16x16x32_bf16(afr1[ks], bf, acc1, 0, 0, 0);
            }
            int c0 = q * 4, c1 = 16 + q * 4;
#pragma unroll
            for (int r = 0; r < 4; ++r) {
                mh[(c0 + r) * 138 + nt * 16 + ln] = f2b(gelu_t(acc0[r] + b1v[nt]));
                mh[(c1 + r) * 138 + nt * 16 + ln] = f2b(gelu_t(acc1[r] + b1v[nt]));
            }
        }
    }

    // ---------------- m2: msg = mh @ mw2^T + mb2 -----------------------------
    {
        v8s afr[2][4];
#pragma unroll
        for (int mi = 0; mi < 2; ++mi) {
            int c = mi * 16 + ln;
#pragma unroll
            for (int ks = 0; ks < 4; ++ks)
                afr[mi][ks] = *(const v8s*)(mh + c * 138 + ks * 32 + q * 8);
        }
        const u16* w2g = mw2b + (size_t)g * DN_ * HM_;
        float mpart[4];
#pragma unroll
        for (int nt = 0; nt < 4; ++nt) {
            float bb = mb2[g * DN_ + nt * 16 + ln];
            v4f acc[2] = {{0,0,0,0},{0,0,0,0}};
#pragma unroll
            for (int ks = 0; ks < 4; ++ks) {
                v8s bf = *(const v8s*)(w2g + (nt * 16 + ln) * HM_ + ks * 32 + q * 8);
#pragma unroll
                for (int mi = 0; mi < 2; ++mi)
                    acc[mi] = __builtin_amdgcn_mfma_f32_16x16x32_bf16(afr[mi][ks], bf, acc[mi], 0, 0, 0);
            }
            float ms = 0.0f;
            int d = nt * 16 + ln;
#pragma unroll
            for (int mi = 0; mi < 2; ++mi) {
                int c = mi * 16 + q * 4;
#pragma unroll
                for (int r = 0; r < 4; ++r) {
                    float mv = acc[mi][r] + bb;
                    am[(c + r) * 74 + d] = f2b(mv);
                    oM[(size_t)(r0 + c + r) * 64 + d] = mv;   // overwrites agg (own rows)
                    ms += mv;
                }
            }
            mpart[nt] = ms;
        }
#pragma unroll
        for (int nt = 0; nt < 4; ++nt) {
            float v = mpart[nt];
            v += __shfl_xor(v, 16);
            v += __shfl_xor(v, 32);
            if (q == 0) partial[pbase + 64 + nt * 16 + ln] = v * (1.0f / 256.0f);
        }
    }

    // ---------------- s1: sh = gelu([h|msg|ctx] @ sw1^T + sb1) ---------------
    {
        v8s cfr0 = cvt8(ctx + (size_t)bnc * DN_ +  0 + q * 8);
        v8s cfr1 = cvt8(ctx + (size_t)bnc * DN_ + 32 + q * 8);
        v8s afr[2][4];
#pragma unroll
        for (int mi = 0; mi < 2; ++mi) {
            int c = mi * 16 + ln;
            afr[mi][0] = hfr[mi][0];
            afr[mi][1] = hfr[mi][1];
            afr[mi][2] = *(const v8s*)(am + c * 74 +  0 + q * 8);
            afr[mi][3] = *(const v8s*)(am + c * 74 + 32 + q * 8);
        }
        float b1v[8];
#pragma unroll
        for (int nt = 0; nt < 8; ++nt) b1v[nt] = sb1[g * HM_ + nt * 16 + ln];
        const u16* w1g = sw1b + (size_t)g * HM_ * F3_;
#pragma unroll
        for (int nt = 0; nt < 8; ++nt) {
            v4f acc[2] = {{0,0,0,0},{0,0,0,0}};
#pragma unroll
            for (int ks = 0; ks < 4; ++ks) {
                v8s bf = *(const v8s*)(w1g + (nt * 16 + ln) * F3_ + ks * 32 + q * 8);
#pragma unroll
                for (int mi = 0; mi < 2; ++mi)
                    acc[mi] = __builtin_amdgcn_mfma_f32_16x16x32_bf16(afr[mi][ks], bf, acc[mi], 0, 0, 0);
            }
#pragma unroll
            for (int ks = 4; ks < 6; ++ks) {
                v8s bf = *(const v8s*)(w1g + (nt * 16 + ln) * F3_ + ks * 32 + q * 8);
                v8s aa = (ks == 4) ? cfr0 : cfr1;   // ctx broadcast across rows
#pragma unroll
                for (int mi = 0; mi < 2; ++mi)
                    acc[mi] = __builtin_amdgcn_mfma_f32_16x16x32_bf16(aa, bf, acc[mi], 0, 0, 0);
            }
#pragma unroll
            for (int mi = 0; mi < 2; ++mi) {
                int c = mi * 16 + q * 4;
#pragma unroll
                for (int r = 0; r < 4; ++r)
                    mh[(c + r) * 138 + nt * 16 + ln] = f2b(gelu_t(acc[mi][r] + b1v[nt]));
            }
        }
    }

    // ---------------- s2: h_new = h(f32) + sh @ sw2^T + sb2 ------------------
    {
        v8s afr[2][4];
#pragma unroll
        for (int mi = 0; mi < 2; ++mi) {
            int c = mi * 16 + ln;
#pragma unroll
            for (int ks = 0; ks < 4; ++ks)
                afr[mi][ks] = *(const v8s*)(mh + c * 138 + ks * 32 + q * 8);
        }
        const u16* w2g = sw2b + (size_t)g * DN_ * HM_;
        float hpart[4];
#pragma unroll
        for (int nt = 0; nt < 4; ++nt) {
            float bb = sb2[g * DN_ + nt * 16 + ln];
            v4f acc[2] = {{0,0,0,0},{0,0,0,0}};
#pragma unroll
            for (int ks = 0; ks < 4; ++ks) {
                v8s bf = *(const v8s*)(w2g + (nt * 16 + ln) * HM_ + ks * 32 + q * 8);
#pragma unroll
                for (int mi = 0; mi < 2; ++mi)
                    acc[mi] = __builtin_amdgcn_mfma_f32_16x16x32_bf16(afr[mi][ks], bf, acc[mi], 0, 0, 0);
            }
            float hs = 0.0f;
            int d = nt * 16 + ln;
#pragma unroll
            for (int mi = 0; mi < 2; ++mi) {
                int c = mi * 16 + q * 4;
#pragma unroll
                for (int r = 0; r < 4; ++r) {
                    float hv = h[hbase + (size_t)(r0 + c + r) * 64 + d];   // f32 residual
                    float hn = hv + acc[mi][r] + bb;
                    oH[(size_t)(r0 + c + r) * 64 + d] = hn;
                    hs += hn;
                }
            }
            hpart[nt] = hs;
        }
#pragma unroll
        for (int nt = 0; nt < 4; ++nt) {
            float v = hpart[nt];
            v += __shfl_xor(v, 16);
            v += __shfl_xor(v, 32);
            if (q == 0) partial[pbase + nt * 16 + ln] = v * (1.0f / 256.0f);
        }
    }
}

// ---- modulation MLP: mod = gelu(p@w1+b1)@w2+b2 -----------------------------
__global__ __launch_bounds__(256) void mg_mod(
    const float* __restrict__ w1, const float* __restrict__ b1,
    const float* __restrict__ w2, const float* __restrict__ b2,
    const float* __restrict__ partial, float* __restrict__ outf)
{
    __shared__ float pool[128];
    __shared__ float ph4[4][64];
    const int bnc = blockIdx.x, n = bnc & 255, t = threadIdx.x;
    if (t < 128) {
        const float* pp = partial + (size_t)bnc * 1024 + t;
        float s = 0.0f;
#pragma unroll
        for (int j = 0; j < 8; ++j) s += pp[j * 128];
        pool[t] = s;
    }
    __syncthreads();
    {
        const int col = t & 63, fh = t >> 6;     // 4-way split over f
        const float* w1p = w1 + ((size_t)n * 128 + fh * 32) * 64 + col;
        float acc = 0.0f;
#pragma unroll
        for (int i = 0; i < 32; ++i)
            acc = __builtin_fmaf(pool[fh * 32 + i], w1p[(size_t)i * 64], acc);
        ph4[fh][col] = acc;
    }
    __syncthreads();
    if (t < 64) {
        float a  = ph4[0][t] + ph4[1][t] + ph4[2][t] + ph4[3][t] + b1[n * 64 + t];
        float ph = gelu_t(a);
        float part5[5];
#pragma unroll
        for (int o = 0; o < 5; ++o) part5[o] = ph * w2[((size_t)n * 64 + t) * 5 + o];
#pragma unroll
        for (int off = 32; off > 0; off >>= 1)
#pragma unroll
            for (int o = 0; o < 5; ++o) part5[o] += __shfl_down(part5[o], off);
        if (t == 0) {
#pragma unroll
            for (int o = 0; o < 5; ++o)
                outf[(size_t)16777216 + bnc * 5 + o] = part5[o] + b2[n * 5 + o];
        }
    }
}

extern "C" void kernel_launch(void* const* d_in, const int* in_sizes, int n_in,
                              void* d_out, int out_size, void* d_ws, size_t ws_size,
                              hipStream_t stream) {
    const float* h     = (const float*)d_in[0];
    const float* wconn = (const float*)d_in[1];
    const float* ctx   = (const float*)d_in[2];
    const float* nid   = (const float*)d_in[3];
    const float* mw1   = (const float*)d_in[4];
    const float* mb1   = (const float*)d_in[5];
    const float* mw2   = (const float*)d_in[6];
    const float* mb2   = (const float*)d_in[7];
    const float* sw1   = (const float*)d_in[8];
    const float* sb1   = (const float*)d_in[9];
    const float* sw2   = (const float*)d_in[10];
    const float* sb2   = (const float*)d_in[11];
    const float* dw1   = (const float*)d_in[12];
    const float* db1   = (const float*)d_in[13];
    const float* dw2   = (const float*)d_in[14];
    const float* db2   = (const float*)d_in[15];
    const int* conn    = (const int*)d_in[16];
    const int* c2g     = (const int*)d_in[17];
    float* outf    = (float*)d_out;
    u16*   wb      = (u16*)d_ws;                        // bf16 weight copies (1 MB)
    float* partial = (float*)((char*)d_ws + 1048576);   // [4096][128] f32 (2 MB)

    cvt_w<<<512, 256, 0, stream>>>(mw1, mw2, sw1, sw2, wb);
    gth<<<4096, 256, 0, stream>>>(h, wconn, conn, outf);
    mg_main<<<4096, 64, 0, stream>>>(h, ctx, nid,
                                     wb,           mb1,
                                     wb + 196608,  mb2,
                                     wb + 262144,  sb1,
                                     wb + 458752,  sb2,
                                     c2g, outf, partial);
    mg_mod<<<512, 256, 0, stream>>>(dw1, db1, dw2, db2, partial, outf);
}

// Round 8
// 243.192 us; speedup vs baseline: 1.0681x; 1.0681x over previous
//
#include <hip/hip_runtime.h>

#define NC_  256
#define CN_  256
#define K_   16
#define DN_  64
#define G_   8
#define HM_  128
#define F3_  192

typedef unsigned short u16;
typedef short v8s __attribute__((ext_vector_type(8)));
typedef float v4f __attribute__((ext_vector_type(4)));

// ---- kernels ---------------------------------------------------------------
// cvt_w   : f32->bf16 weight tables into d_ws (1 MB)
// gth     : gather agg = sum_k w*h[nbr]; h staged in LDS as bf16 (32 KB/block);
//           agg f32 -> oM region (indices msg later overwrites, same block map)
// mg_main : 1-wave blocks (64 thr), 32 rows each, no barriers; single aliased
//           LDS buffer [32][138] (8832 B) serves mh AND msg transposes
// mg_mod  : modulation MLP from pooled partials
//
// d_ws: bf16 weights @0 (1 MB), partial f32 [4096][128] @ byte 1048576 (2 MB)

__device__ __forceinline__ u16 f2b(float f) {
    unsigned v; __builtin_memcpy(&v, &f, 4);
    v = v + 0x7fffu + ((v >> 16) & 1u);   // RNE
    return (u16)(v >> 16);
}
__device__ __forceinline__ v8s cvt8(const float* p) {
    float4 a = *(const float4*)p, b = *(const float4*)(p + 4);
    v8s r;
    r[0] = (short)f2b(a.x); r[1] = (short)f2b(a.y); r[2] = (short)f2b(a.z); r[3] = (short)f2b(a.w);
    r[4] = (short)f2b(b.x); r[5] = (short)f2b(b.y); r[6] = (short)f2b(b.z); r[7] = (short)f2b(b.w);
    return r;
}
__device__ __forceinline__ float gelu_t(float x) {
    // jax.nn.gelu approximate=True: x*sigmoid(2*k0*x*(1+k1*x^2))
    float u = x * x;
    float t = 1.5957691216057308f * x * __builtin_fmaf(0.044715f, u, 1.0f);
    float e = __expf(-t);
    return x * __builtin_amdgcn_rcpf(1.0f + e);
}

__global__ __launch_bounds__(256) void cvt_w(
    const float* __restrict__ mw1, const float* __restrict__ mw2,
    const float* __restrict__ sw1, const float* __restrict__ sw2,
    u16* __restrict__ dst)
{
    int e = (blockIdx.x * 256 + threadIdx.x) * 4;   // 131072 threads * 4 = 524288
    const float* s; int off;
    if      (e < 196608) { s = mw1; off = e; }
    else if (e < 262144) { s = mw2; off = e - 196608; }
    else if (e < 458752) { s = sw1; off = e - 262144; }
    else                 { s = sw2; off = e - 458752; }
    float4 v = *(const float4*)(s + off);
    ushort4 o4;
    o4.x = f2b(v.x); o4.y = f2b(v.y); o4.z = f2b(v.z); o4.w = f2b(v.w);
    *(ushort4*)(dst + e) = o4;
}

// ---- gather: h staged in LDS (bf16), 128 rows per block --------------------
// p = x(3b) | c6(6b) | half(1b): bnc = x*64 + c6 (XCD x owns cells [x*64,x*64+64)
// in BOTH gth and mg_main so the cell's data stays in one XCD L2).
__global__ __launch_bounds__(256) void gth(
    const float* __restrict__ h, const float* __restrict__ wconn,
    const int* __restrict__ conn, float* __restrict__ outf)
{
    __shared__ u16 hl[16384];                     // [256][64] bf16 = 32 KB
    const int p    = blockIdx.x;                  // 0..1023
    const int bnc  = (p & 7) * 64 + ((p >> 3) & 63);
    const int half = p >> 9;
    const int tid  = threadIdx.x;
    const int wave = tid >> 6, lane = tid & 63;
    const int r0   = half * 128 + wave * 32;      // 32 rows per wave
    const int n    = bnc & 255;
    const size_t hb = (size_t)bnc * 16384;

    // stage: coalesced 4KB/instr; LDS writes linear (conflict-free)
#pragma unroll
    for (int i = 0; i < 16; ++i) {
        float4 v = *(const float4*)(h + hb + tid * 4 + i * 1024);
        ushort4 o;
        o.x = f2b(v.x); o.y = f2b(v.y); o.z = f2b(v.z); o.w = f2b(v.w);
        *(ushort4*)(hl + tid * 4 + i * 1024) = o;
    }
    __syncthreads();

    float* aggo = outf + (size_t)8388608 + hb;    // oM region, f32, msg indices
    const int*   __restrict__ cp = conn  + n * 4096 + r0 * 16;
    const float* __restrict__ wp = wconn + (size_t)bnc * 4096 + (size_t)r0 * 16;
    int iv = cp[lane]; float wv = wp[lane];       // 4 rows' (idx,w) per 64-lane load
    for (int g4 = 0; g4 < 8; ++g4) {
        int ivn = 0; float wvn = 0.0f;
        if (g4 < 7) { ivn = cp[(g4 + 1) * 64 + lane]; wvn = wp[(g4 + 1) * 64 + lane]; }
#pragma unroll
        for (int r = 0; r < 4; ++r) {
            float a0 = 0.0f, a1 = 0.0f;
#pragma unroll
            for (int k = 0; k < 16; k += 2) {
                const int l0 = r * 16 + k;
                int   i0 = __builtin_amdgcn_readlane(iv, l0);
                int   i1 = __builtin_amdgcn_readlane(iv, l0 + 1);
                float w0 = __int_as_float(__builtin_amdgcn_readlane(__float_as_int(wv), l0));
                float w1 = __int_as_float(__builtin_amdgcn_readlane(__float_as_int(wv), l0 + 1));
                unsigned h0 = (unsigned)hl[i0 * 64 + lane] << 16;
                unsigned h1 = (unsigned)hl[i1 * 64 + lane] << 16;
                a0 = __builtin_fmaf(w0, __uint_as_float(h0), a0);
                a1 = __builtin_fmaf(w1, __uint_as_float(h1), a1);
            }
            aggo[(size_t)(r0 + g4 * 4 + r) * 64 + lane] = a0 + a1;
        }
        iv = ivn; wv = wvn;
    }
}

// ---- main MLP chain: 1 wave / 32 rows, no barriers, single LDS buffer ------
__global__ __launch_bounds__(64, 4) void mg_main(
    const float* __restrict__ h,    const float* __restrict__ ctx,
    const float* __restrict__ nid,
    const u16* __restrict__ mw1b,   const float* __restrict__ mb1,
    const u16* __restrict__ mw2b,   const float* __restrict__ mb2,
    const u16* __restrict__ sw1b,   const float* __restrict__ sb1,
    const u16* __restrict__ sw2b,   const float* __restrict__ sb2,
    const int* __restrict__ c2g,
    float* __restrict__ outf,       float* __restrict__ partial)
{
    const int p     = blockIdx.x;                 // 0..4095
    const int bnc   = (p & 7) * 64 + (p >> 6);    // same XCD map as gth
    const int chunk = (p >> 3) & 7;
    const int r0    = chunk * 32;
    const int n     = bnc & 255;
    const int g     = c2g[n];
    const int lane  = threadIdx.x;
    const int q     = lane >> 4, ln = lane & 15;

    // Single buffer, aliased across phases (per-wave DS ordering guarantees
    // read-before-overwrite): m1 writes cols 0..127 (mh); m2 reads all, then
    // writes msg into cols 0..63; s1 reads msg frags, then writes sh 0..127;
    // s2 reads sh.
    __shared__ u16 buf[32 * 138];   // 8832 B

    const size_t hbase = (size_t)bnc * 16384;
    const size_t nbase = (size_t)n   * 16384;
    float* oH = outf + hbase;
    float* oM = outf + (size_t)8388608 + hbase;   // holds agg (f32) until m2
    const size_t pbase = (size_t)(bnc * 8 + chunk) * 128;

    // ---------------- A-fragments straight from global (L2-hot) --------------
    v8s hfr[2][2], gfr[2][2], nfr[2][2];
#pragma unroll
    for (int mi = 0; mi < 2; ++mi) {
        int c = r0 + mi * 16 + ln;
        hfr[mi][0] = cvt8(h   + hbase + (size_t)c * 64 +  0 + q * 8);
        hfr[mi][1] = cvt8(h   + hbase + (size_t)c * 64 + 32 + q * 8);
        gfr[mi][0] = cvt8(oM  + (size_t)c * 64 +  0 + q * 8);        // agg
        gfr[mi][1] = cvt8(oM  + (size_t)c * 64 + 32 + q * 8);
        nfr[mi][0] = cvt8(nid + nbase + (size_t)c * 64 +  0 + q * 8);
        nfr[mi][1] = cvt8(nid + nbase + (size_t)c * 64 + 32 + q * 8);
    }

    // ---------------- m1: mh = gelu([h|agg|nid] @ mw1^T + mb1) ---------------
    {
        v8s afr0[6] = {hfr[0][0], hfr[0][1], gfr[0][0], gfr[0][1], nfr[0][0], nfr[0][1]};
        v8s afr1[6] = {hfr[1][0], hfr[1][1], gfr[1][0], gfr[1][1], nfr[1][0], nfr[1][1]};
        float b1v[8];
#pragma unroll
        for (int nt = 0; nt < 8; ++nt) b1v[nt] = mb1[g * HM_ + nt * 16 + ln];
        const u16* w1g = mw1b + (size_t)g * HM_ * F3_;
#pragma unroll
        for (int nt = 0; nt < 8; ++nt) {
            v4f acc0 = {0,0,0,0}, acc1 = {0,0,0,0};
#pragma unroll
            for (int ks = 0; ks < 6; ++ks) {
                v8s bf = *(const v8s*)(w1g + (nt * 16 + ln) * F3_ + ks * 32 + q * 8);
                acc0 = __builtin_amdgcn_mfma_f32_16x16x32_bf16(afr0[ks], bf, acc0, 0, 0, 0);
                acc1 = __builtin_amdgcn_mfma_f32_16x16x32_bf16(afr1[ks], bf, acc1, 0, 0, 0);
            }
            int c0 = q * 4, c1 = 16 + q * 4;
#pragma unroll
            for (int r = 0; r < 4; ++r) {
                buf[(c0 + r) * 138 + nt * 16 + ln] = f2b(gelu_t(acc0[r] + b1v[nt]));
                buf[(c1 + r) * 138 + nt * 16 + ln] = f2b(gelu_t(acc1[r] + b1v[nt]));
            }
        }
    }

    // ---------------- m2: msg = mh @ mw2^T + mb2 -----------------------------
    {
        v8s afr[2][4];                            // read ALL of mh first
#pragma unroll
        for (int mi = 0; mi < 2; ++mi) {
            int c = mi * 16 + ln;
#pragma unroll
            for (int ks = 0; ks < 4; ++ks)
                afr[mi][ks] = *(const v8s*)(buf + c * 138 + ks * 32 + q * 8);
        }
        const u16* w2g = mw2b + (size_t)g * DN_ * HM_;
        float mpart[4];
#pragma unroll
        for (int nt = 0; nt < 4; ++nt) {
            float bb = mb2[g * DN_ + nt * 16 + ln];
            v4f acc[2] = {{0,0,0,0},{0,0,0,0}};
#pragma unroll
            for (int ks = 0; ks < 4; ++ks) {
                v8s bf = *(const v8s*)(w2g + (nt * 16 + ln) * HM_ + ks * 32 + q * 8);
#pragma unroll
                for (int mi = 0; mi < 2; ++mi)
                    acc[mi] = __builtin_amdgcn_mfma_f32_16x16x32_bf16(afr[mi][ks], bf, acc[mi], 0, 0, 0);
            }
            float ms = 0.0f;
            int d = nt * 16 + ln;
#pragma unroll
            for (int mi = 0; mi < 2; ++mi) {
                int c = mi * 16 + q * 4;
#pragma unroll
                for (int r = 0; r < 4; ++r) {
                    float mv = acc[mi][r] + bb;
                    buf[(c + r) * 138 + d] = f2b(mv);             // msg -> cols 0..63
                    oM[(size_t)(r0 + c + r) * 64 + d] = mv;       // overwrites agg
                    ms += mv;
                }
            }
            mpart[nt] = ms;
        }
#pragma unroll
        for (int nt = 0; nt < 4; ++nt) {
            float v = mpart[nt];
            v += __shfl_xor(v, 16);
            v += __shfl_xor(v, 32);
            if (q == 0) partial[pbase + 64 + nt * 16 + ln] = v * (1.0f / 256.0f);
        }
    }

    // ---------------- s1: sh = gelu([h|msg|ctx] @ sw1^T + sb1) ---------------
    {
        v8s cfr0 = cvt8(ctx + (size_t)bnc * DN_ +  0 + q * 8);
        v8s cfr1 = cvt8(ctx + (size_t)bnc * DN_ + 32 + q * 8);
        v8s afr[2][4];                            // read msg frags BEFORE sh writes
#pragma unroll
        for (int mi = 0; mi < 2; ++mi) {
            int c = mi * 16 + ln;
            afr[mi][0] = hfr[mi][0];
            afr[mi][1] = hfr[mi][1];
            afr[mi][2] = *(const v8s*)(buf + c * 138 +  0 + q * 8);
            afr[mi][3] = *(const v8s*)(buf + c * 138 + 32 + q * 8);
        }
        float b1v[8];
#pragma unroll
        for (int nt = 0; nt < 8; ++nt) b1v[nt] = sb1[g * HM_ + nt * 16 + ln];
        const u16* w1g = sw1b + (size_t)g * HM_ * F3_;
#pragma unroll
        for (int nt = 0; nt < 8; ++nt) {
            v4f acc[2] = {{0,0,0,0},{0,0,0,0}};
#pragma unroll
            for (int ks = 0; ks < 4; ++ks) {
                v8s bf = *(const v8s*)(w1g + (nt * 16 + ln) * F3_ + ks * 32 + q * 8);
#pragma unroll
                for (int mi = 0; mi < 2; ++mi)
                    acc[mi] = __builtin_amdgcn_mfma_f32_16x16x32_bf16(afr[mi][ks], bf, acc[mi], 0, 0, 0);
            }
#pragma unroll
            for (int ks = 4; ks < 6; ++ks) {
                v8s bf = *(const v8s*)(w1g + (nt * 16 + ln) * F3_ + ks * 32 + q * 8);
                v8s aa = (ks == 4) ? cfr0 : cfr1;   // ctx broadcast across rows
#pragma unroll
                for (int mi = 0; mi < 2; ++mi)
                    acc[mi] = __builtin_amdgcn_mfma_f32_16x16x32_bf16(aa, bf, acc[mi], 0, 0, 0);
            }
#pragma unroll
            for (int mi = 0; mi < 2; ++mi) {
                int c = mi * 16 + q * 4;
#pragma unroll
                for (int r = 0; r < 4; ++r)
                    buf[(c + r) * 138 + nt * 16 + ln] = f2b(gelu_t(acc[mi][r] + b1v[nt]));
            }
        }
    }

    // ---------------- s2: h_new = h(f32) + sh @ sw2^T + sb2 ------------------
    {
        v8s afr[2][4];
#pragma unroll
        for (int mi = 0; mi < 2; ++mi) {
            int c = mi * 16 + ln;
#pragma unroll
            for (int ks = 0; ks < 4; ++ks)
                afr[mi][ks] = *(const v8s*)(buf + c * 138 + ks * 32 + q * 8);
        }
        const u16* w2g = sw2b + (size_t)g * DN_ * HM_;
        float hpart[4];
#pragma unroll
        for (int nt = 0; nt < 4; ++nt) {
            float bb = sb2[g * DN_ + nt * 16 + ln];
            v4f acc[2] = {{0,0,0,0},{0,0,0,0}};
#pragma unroll
            for (int ks = 0; ks < 4; ++ks) {
                v8s bf = *(const v8s*)(w2g + (nt * 16 + ln) * HM_ + ks * 32 + q * 8);
#pragma unroll
                for (int mi = 0; mi < 2; ++mi)
                    acc[mi] = __builtin_amdgcn_mfma_f32_16x16x32_bf16(afr[mi][ks], bf, acc[mi], 0, 0, 0);
            }
            float hs = 0.0f;
            int d = nt * 16 + ln;
#pragma unroll
            for (int mi = 0; mi < 2; ++mi) {
                int c = mi * 16 + q * 4;
#pragma unroll
                for (int r = 0; r < 4; ++r) {
                    float hv = h[hbase + (size_t)(r0 + c + r) * 64 + d];   // f32 residual
                    float hn = hv + acc[mi][r] + bb;
                    oH[(size_t)(r0 + c + r) * 64 + d] = hn;
                    hs += hn;
                }
            }
            hpart[nt] = hs;
        }
#pragma unroll
        for (int nt = 0; nt < 4; ++nt) {
            float v = hpart[nt];
            v += __shfl_xor(v, 16);
            v += __shfl_xor(v, 32);
            if (q == 0) partial[pbase + nt * 16 + ln] = v * (1.0f / 256.0f);
        }
    }
}

// ---- modulation MLP: mod = gelu(p@w1+b1)@w2+b2 -----------------------------
__global__ __launch_bounds__(256) void mg_mod(
    const float* __restrict__ w1, const float* __restrict__ b1,
    const float* __restrict__ w2, const float* __restrict__ b2,
    const float* __restrict__ partial, float* __restrict__ outf)
{
    __shared__ float pool[128];
    __shared__ float ph4[4][64];
    const int bnc = blockIdx.x, n = bnc & 255, t = threadIdx.x;
    if (t < 128) {
        const float* pp = partial + (size_t)bnc * 1024 + t;
        float s = 0.0f;
#pragma unroll
        for (int j = 0; j < 8; ++j) s += pp[j * 128];
        pool[t] = s;
    }
    __syncthreads();
    {
        const int col = t & 63, fh = t >> 6;     // 4-way split over f
        const float* w1p = w1 + ((size_t)n * 128 + fh * 32) * 64 + col;
        float acc = 0.0f;
#pragma unroll
        for (int i = 0; i < 32; ++i)
            acc = __builtin_fmaf(pool[fh * 32 + i], w1p[(size_t)i * 64], acc);
        ph4[fh][col] = acc;
    }
    __syncthreads();
    if (t < 64) {
        float a  = ph4[0][t] + ph4[1][t] + ph4[2][t] + ph4[3][t] + b1[n * 64 + t];
        float ph = gelu_t(a);
        float part5[5];
#pragma unroll
        for (int o = 0; o < 5; ++o) part5[o] = ph * w2[((size_t)n * 64 + t) * 5 + o];
#pragma unroll
        for (int off = 32; off > 0; off >>= 1)
#pragma unroll
            for (int o = 0; o < 5; ++o) part5[o] += __shfl_down(part5[o], off);
        if (t == 0) {
#pragma unroll
            for (int o = 0; o < 5; ++o)
                outf[(size_t)16777216 + bnc * 5 + o] = part5[o] + b2[n * 5 + o];
        }
    }
}

extern "C" void kernel_launch(void* const* d_in, const int* in_sizes, int n_in,
                              void* d_out, int out_size, void* d_ws, size_t ws_size,
                              hipStream_t stream) {
    const float* h     = (const float*)d_in[0];
    const float* wconn = (const float*)d_in[1];
    const float* ctx   = (const float*)d_in[2];
    const float* nid   = (const float*)d_in[3];
    const float* mw1   = (const float*)d_in[4];
    const float* mb1   = (const float*)d_in[5];
    const float* mw2   = (const float*)d_in[6];
    const float* mb2   = (const float*)d_in[7];
    const float* sw1   = (const float*)d_in[8];
    const float* sb1   = (const float*)d_in[9];
    const float* sw2   = (const float*)d_in[10];
    const float* sb2   = (const float*)d_in[11];
    const float* dw1   = (const float*)d_in[12];
    const float* db1   = (const float*)d_in[13];
    const float* dw2   = (const float*)d_in[14];
    const float* db2   = (const float*)d_in[15];
    const int* conn    = (const int*)d_in[16];
    const int* c2g     = (const int*)d_in[17];
    float* outf    = (float*)d_out;
    u16*   wb      = (u16*)d_ws;                        // bf16 weight copies (1 MB)
    float* partial = (float*)((char*)d_ws + 1048576);   // [4096][128] f32 (2 MB)

    cvt_w<<<512, 256, 0, stream>>>(mw1, mw2, sw1, sw2, wb);
    gth<<<1024, 256, 0, stream>>>(h, wconn, conn, outf);
    mg_main<<<4096, 64, 0, stream>>>(h, ctx, nid,
                                     wb,           mb1,
                                     wb + 196608,  mb2,
                                     wb + 262144,  sb1,
                                     wb + 458752,  sb2,
                                     c2g, outf, partial);
    mg_mod<<<512, 256, 0, stream>>>(dw1, db1, dw2, db2, partial, outf);
}

// Round 9
// 215.817 us; speedup vs baseline: 1.2036x; 1.1268x over previous
//
#include <hip/hip_runtime.h>

#define NC_  256
#define CN_  256
#define K_   16
#define DN_  64
#define G_   8
#define HM_  128
#define F3_  192

typedef unsigned short u16;
typedef short v8s __attribute__((ext_vector_type(8)));
typedef float v4f __attribute__((ext_vector_type(4)));

// ---- kernels ---------------------------------------------------------------
// cvt_w   : f32->bf16 weight tables into d_ws (1 MB)
// mg_main : FUSED gather + MLP chain. 1-wave blocks (64 thr), 64 rows each,
//           no barriers. Gather reads h from L2 (f32) and writes agg bf16 into
//           the single aliased LDS buffer; the MLP chain consumes it directly.
//           No agg HBM round-trip, no separate gth dispatch.
// mg_mod  : modulation MLP from pooled partials
//
// d_ws: bf16 weights @0 (1 MB), partial f32 [2048][128] @ byte 1048576 (1 MB)

__device__ __forceinline__ u16 f2b(float f) {
    unsigned v; __builtin_memcpy(&v, &f, 4);
    v = v + 0x7fffu + ((v >> 16) & 1u);   // RNE
    return (u16)(v >> 16);
}
__device__ __forceinline__ v8s cvt8(const float* p) {
    float4 a = *(const float4*)p, b = *(const float4*)(p + 4);
    v8s r;
    r[0] = (short)f2b(a.x); r[1] = (short)f2b(a.y); r[2] = (short)f2b(a.z); r[3] = (short)f2b(a.w);
    r[4] = (short)f2b(b.x); r[5] = (short)f2b(b.y); r[6] = (short)f2b(b.z); r[7] = (short)f2b(b.w);
    return r;
}
__device__ __forceinline__ float gelu_t(float x) {
    // jax.nn.gelu approximate=True: x*sigmoid(2*k0*x*(1+k1*x^2))
    float u = x * x;
    float t = 1.5957691216057308f * x * __builtin_fmaf(0.044715f, u, 1.0f);
    float e = __expf(-t);
    return x * __builtin_amdgcn_rcpf(1.0f + e);
}

__global__ __launch_bounds__(256) void cvt_w(
    const float* __restrict__ mw1, const float* __restrict__ mw2,
    const float* __restrict__ sw1, const float* __restrict__ sw2,
    u16* __restrict__ dst)
{
    int e = (blockIdx.x * 256 + threadIdx.x) * 4;   // 131072 threads * 4 = 524288
    const float* s; int off;
    if      (e < 196608) { s = mw1; off = e; }
    else if (e < 262144) { s = mw2; off = e - 196608; }
    else if (e < 458752) { s = sw1; off = e - 262144; }
    else                 { s = sw2; off = e - 458752; }
    float4 v = *(const float4*)(s + off);
    ushort4 o4;
    o4.x = f2b(v.x); o4.y = f2b(v.y); o4.z = f2b(v.z); o4.w = f2b(v.w);
    *(ushort4*)(dst + e) = o4;
}

// ---- fused gather + MLP chain: 1 wave / 64 rows, no barriers ---------------
// p = c6(6b) | quart(2b) | xcd(3b): bnc = xcd*64 + c6 keeps a cell's data in
// one XCD's L2.
__global__ __launch_bounds__(64, 2) void mg_main(
    const float* __restrict__ h,    const float* __restrict__ wconn,
    const float* __restrict__ ctx,  const float* __restrict__ nid,
    const u16* __restrict__ mw1b,   const float* __restrict__ mb1,
    const u16* __restrict__ mw2b,   const float* __restrict__ mb2,
    const u16* __restrict__ sw1b,   const float* __restrict__ sb1,
    const u16* __restrict__ sw2b,   const float* __restrict__ sb2,
    const int* __restrict__ conn,   const int* __restrict__ c2g,
    float* __restrict__ outf,       float* __restrict__ partial)
{
    const int p     = blockIdx.x;                 // 0..2047
    const int bnc   = (p & 7) * 64 + (p >> 5);
    const int quart = (p >> 3) & 3;
    const int r0    = quart * 64;                 // this wave's 64 rows
    const int n     = bnc & 255;
    const int g     = c2g[n];
    const int lane  = threadIdx.x;
    const int q     = lane >> 4, ln = lane & 15;

    // Single aliased buffer (per-wave DS ordering = read-before-overwrite):
    // gather writes agg cols 0..63; frag-preload reads it; m1 writes mh
    // cols 0..127; m2 reads mh then writes msg cols 0..63; s1 reads msg then
    // writes sh; s2 reads sh.
    __shared__ u16 buf[64 * 138];   // 17664 B

    const size_t hbase = (size_t)bnc * 16384;
    const size_t nbase = (size_t)n   * 16384;
    float* oH = outf + hbase;
    float* oM = outf + (size_t)8388608 + hbase;
    const size_t pbase = (size_t)(bnc * 4 + quart) * 128;

    // ---------------- gather: agg[c][d] = sum_k w*h[nbr], h from L2 (f32) ----
    {
        const float* __restrict__ hp = h + hbase;
        const int*   __restrict__ cp = conn  + n * 4096 + r0 * 16;
        const float* __restrict__ wp = wconn + (size_t)bnc * 4096 + (size_t)r0 * 16;
        int iv = cp[lane]; float wv = wp[lane];   // 4 rows' (idx,w) per 64-lane load
        for (int g4 = 0; g4 < 16; ++g4) {
            int ivn = 0; float wvn = 0.0f;
            if (g4 < 15) { ivn = cp[(g4 + 1) * 64 + lane]; wvn = wp[(g4 + 1) * 64 + lane]; }
#pragma unroll
            for (int r = 0; r < 4; ++r) {
                float a0 = 0.0f, a1 = 0.0f;
#pragma unroll
                for (int k = 0; k < 16; k += 2) {
                    const int l0 = r * 16 + k;
                    int   i0 = __builtin_amdgcn_readlane(iv, l0);
                    int   i1 = __builtin_amdgcn_readlane(iv, l0 + 1);
                    float w0 = __int_as_float(__builtin_amdgcn_readlane(__float_as_int(wv), l0));
                    float w1 = __int_as_float(__builtin_amdgcn_readlane(__float_as_int(wv), l0 + 1));
                    a0 = __builtin_fmaf(w0, hp[i0 * 64 + lane], a0);   // 256B coalesced
                    a1 = __builtin_fmaf(w1, hp[i1 * 64 + lane], a1);
                }
                buf[(g4 * 4 + r) * 138 + lane] = f2b(a0 + a1);
            }
            iv = ivn; wv = wvn;
        }
    }

    // ---------------- A-fragments (agg from buf; h/nid from global L2) -------
    v8s hfr[4][2], gfr[4][2], nfr[4][2];
#pragma unroll
    for (int mi = 0; mi < 4; ++mi) {
        int c  = r0 + mi * 16 + ln;
        int lc = mi * 16 + ln;
        hfr[mi][0] = cvt8(h + hbase + (size_t)c * 64 +  0 + q * 8);
        hfr[mi][1] = cvt8(h + hbase + (size_t)c * 64 + 32 + q * 8);
        gfr[mi][0] = *(const v8s*)(buf + lc * 138 +  0 + q * 8);
        gfr[mi][1] = *(const v8s*)(buf + lc * 138 + 32 + q * 8);
        nfr[mi][0] = cvt8(nid + nbase + (size_t)c * 64 +  0 + q * 8);
        nfr[mi][1] = cvt8(nid + nbase + (size_t)c * 64 + 32 + q * 8);
    }

    // ---------------- m1: mh = gelu([h|agg|nid] @ mw1^T + mb1) ---------------
    {
        float b1v[8];
#pragma unroll
        for (int nt = 0; nt < 8; ++nt) b1v[nt] = mb1[g * HM_ + nt * 16 + ln];
        const u16* w1g = mw1b + (size_t)g * HM_ * F3_;
#pragma unroll
        for (int nt = 0; nt < 8; ++nt) {
            v4f acc[4] = {{0,0,0,0},{0,0,0,0},{0,0,0,0},{0,0,0,0}};
#pragma unroll
            for (int ks = 0; ks < 6; ++ks) {
                v8s bf = *(const v8s*)(w1g + (nt * 16 + ln) * F3_ + ks * 32 + q * 8);
#pragma unroll
                for (int mi = 0; mi < 4; ++mi) {
                    v8s aa = (ks < 2) ? hfr[mi][ks] : (ks < 4) ? gfr[mi][ks - 2] : nfr[mi][ks - 4];
                    acc[mi] = __builtin_amdgcn_mfma_f32_16x16x32_bf16(aa, bf, acc[mi], 0, 0, 0);
                }
            }
#pragma unroll
            for (int mi = 0; mi < 4; ++mi) {
                int c = mi * 16 + q * 4;
#pragma unroll
                for (int r = 0; r < 4; ++r)
                    buf[(c + r) * 138 + nt * 16 + ln] = f2b(gelu_t(acc[mi][r] + b1v[nt]));
            }
        }
    }

    // ---------------- m2: msg = mh @ mw2^T + mb2 -----------------------------
    {
        v8s afr[4][4];                            // read ALL of mh first
#pragma unroll
        for (int mi = 0; mi < 4; ++mi) {
            int c = mi * 16 + ln;
#pragma unroll
            for (int ks = 0; ks < 4; ++ks)
                afr[mi][ks] = *(const v8s*)(buf + c * 138 + ks * 32 + q * 8);
        }
        const u16* w2g = mw2b + (size_t)g * DN_ * HM_;
        float mpart[4];
#pragma unroll
        for (int nt = 0; nt < 4; ++nt) {
            float bb = mb2[g * DN_ + nt * 16 + ln];
            v4f acc[4] = {{0,0,0,0},{0,0,0,0},{0,0,0,0},{0,0,0,0}};
#pragma unroll
            for (int ks = 0; ks < 4; ++ks) {
                v8s bf = *(const v8s*)(w2g + (nt * 16 + ln) * HM_ + ks * 32 + q * 8);
#pragma unroll
                for (int mi = 0; mi < 4; ++mi)
                    acc[mi] = __builtin_amdgcn_mfma_f32_16x16x32_bf16(afr[mi][ks], bf, acc[mi], 0, 0, 0);
            }
            float ms = 0.0f;
            int d = nt * 16 + ln;
#pragma unroll
            for (int mi = 0; mi < 4; ++mi) {
                int c = mi * 16 + q * 4;
#pragma unroll
                for (int r = 0; r < 4; ++r) {
                    float mv = acc[mi][r] + bb;
                    buf[(c + r) * 138 + d] = f2b(mv);             // msg -> cols 0..63
                    oM[(size_t)(r0 + c + r) * 64 + d] = mv;
                    ms += mv;
                }
            }
            mpart[nt] = ms;
        }
#pragma unroll
        for (int nt = 0; nt < 4; ++nt) {
            float v = mpart[nt];
            v += __shfl_xor(v, 16);
            v += __shfl_xor(v, 32);
            if (q == 0) partial[pbase + 64 + nt * 16 + ln] = v * (1.0f / 256.0f);
        }
    }

    // ---------------- s1: sh = gelu([h|msg|ctx] @ sw1^T + sb1) ---------------
    {
        v8s cfr0 = cvt8(ctx + (size_t)bnc * DN_ +  0 + q * 8);
        v8s cfr1 = cvt8(ctx + (size_t)bnc * DN_ + 32 + q * 8);
        v8s mfr[4][2];                            // read msg frags BEFORE sh writes
#pragma unroll
        for (int mi = 0; mi < 4; ++mi) {
            int c = mi * 16 + ln;
            mfr[mi][0] = *(const v8s*)(buf + c * 138 +  0 + q * 8);
            mfr[mi][1] = *(const v8s*)(buf + c * 138 + 32 + q * 8);
        }
        float b1v[8];
#pragma unroll
        for (int nt = 0; nt < 8; ++nt) b1v[nt] = sb1[g * HM_ + nt * 16 + ln];
        const u16* w1g = sw1b + (size_t)g * HM_ * F3_;
#pragma unroll
        for (int nt = 0; nt < 8; ++nt) {
            v4f acc[4] = {{0,0,0,0},{0,0,0,0},{0,0,0,0},{0,0,0,0}};
#pragma unroll
            for (int ks = 0; ks < 4; ++ks) {
                v8s bf = *(const v8s*)(w1g + (nt * 16 + ln) * F3_ + ks * 32 + q * 8);
#pragma unroll
                for (int mi = 0; mi < 4; ++mi) {
                    v8s aa = (ks < 2) ? hfr[mi][ks] : mfr[mi][ks - 2];
                    acc[mi] = __builtin_amdgcn_mfma_f32_16x16x32_bf16(aa, bf, acc[mi], 0, 0, 0);
                }
            }
#pragma unroll
            for (int ks = 4; ks < 6; ++ks) {
                v8s bf = *(const v8s*)(w1g + (nt * 16 + ln) * F3_ + ks * 32 + q * 8);
                v8s aa = (ks == 4) ? cfr0 : cfr1;   // ctx broadcast across rows
#pragma unroll
                for (int mi = 0; mi < 4; ++mi)
                    acc[mi] = __builtin_amdgcn_mfma_f32_16x16x32_bf16(aa, bf, acc[mi], 0, 0, 0);
            }
#pragma unroll
            for (int mi = 0; mi < 4; ++mi) {
                int c = mi * 16 + q * 4;
#pragma unroll
                for (int r = 0; r < 4; ++r)
                    buf[(c + r) * 138 + nt * 16 + ln] = f2b(gelu_t(acc[mi][r] + b1v[nt]));
            }
        }
    }

    // ---------------- s2: h_new = h(f32) + sh @ sw2^T + sb2 ------------------
    {
        v8s afr[4][4];
#pragma unroll
        for (int mi = 0; mi < 4; ++mi) {
            int c = mi * 16 + ln;
#pragma unroll
            for (int ks = 0; ks < 4; ++ks)
                afr[mi][ks] = *(const v8s*)(buf + c * 138 + ks * 32 + q * 8);
        }
        const u16* w2g = sw2b + (size_t)g * DN_ * HM_;
        float hpart[4];
#pragma unroll
        for (int nt = 0; nt < 4; ++nt) {
            float bb = sb2[g * DN_ + nt * 16 + ln];
            v4f acc[4] = {{0,0,0,0},{0,0,0,0},{0,0,0,0},{0,0,0,0}};
#pragma unroll
            for (int ks = 0; ks < 4; ++ks) {
                v8s bf = *(const v8s*)(w2g + (nt * 16 + ln) * HM_ + ks * 32 + q * 8);
#pragma unroll
                for (int mi = 0; mi < 4; ++mi)
                    acc[mi] = __builtin_amdgcn_mfma_f32_16x16x32_bf16(afr[mi][ks], bf, acc[mi], 0, 0, 0);
            }
            float hs = 0.0f;
            int d = nt * 16 + ln;
#pragma unroll
            for (int mi = 0; mi < 4; ++mi) {
                int c = mi * 16 + q * 4;
#pragma unroll
                for (int r = 0; r < 4; ++r) {
                    float hv = h[hbase + (size_t)(r0 + c + r) * 64 + d];   // f32 residual
                    float hn = hv + acc[mi][r] + bb;
                    oH[(size_t)(r0 + c + r) * 64 + d] = hn;
                    hs += hn;
                }
            }
            hpart[nt] = hs;
        }
#pragma unroll
        for (int nt = 0; nt < 4; ++nt) {
            float v = hpart[nt];
            v += __shfl_xor(v, 16);
            v += __shfl_xor(v, 32);
            if (q == 0) partial[pbase + nt * 16 + ln] = v * (1.0f / 256.0f);
        }
    }
}

// ---- modulation MLP: mod = gelu(p@w1+b1)@w2+b2 -----------------------------
__global__ __launch_bounds__(256) void mg_mod(
    const float* __restrict__ w1, const float* __restrict__ b1,
    const float* __restrict__ w2, const float* __restrict__ b2,
    const float* __restrict__ partial, float* __restrict__ outf)
{
    __shared__ float pool[128];
    __shared__ float ph4[4][64];
    const int bnc = blockIdx.x, n = bnc & 255, t = threadIdx.x;
    if (t < 128) {
        const float* pp = partial + (size_t)bnc * 512 + t;
        float s = 0.0f;
#pragma unroll
        for (int j = 0; j < 4; ++j) s += pp[j * 128];
        pool[t] = s;
    }
    __syncthreads();
    {
        const int col = t & 63, fh = t >> 6;     // 4-way split over f
        const float* w1p = w1 + ((size_t)n * 128 + fh * 32) * 64 + col;
        float acc = 0.0f;
#pragma unroll
        for (int i = 0; i < 32; ++i)
            acc = __builtin_fmaf(pool[fh * 32 + i], w1p[(size_t)i * 64], acc);
        ph4[fh][col] = acc;
    }
    __syncthreads();
    if (t < 64) {
        float a  = ph4[0][t] + ph4[1][t] + ph4[2][t] + ph4[3][t] + b1[n * 64 + t];
        float ph = gelu_t(a);
        float part5[5];
#pragma unroll
        for (int o = 0; o < 5; ++o) part5[o] = ph * w2[((size_t)n * 64 + t) * 5 + o];
#pragma unroll
        for (int off = 32; off > 0; off >>= 1)
#pragma unroll
            for (int o = 0; o < 5; ++o) part5[o] += __shfl_down(part5[o], off);
        if (t == 0) {
#pragma unroll
            for (int o = 0; o < 5; ++o)
                outf[(size_t)16777216 + bnc * 5 + o] = part5[o] + b2[n * 5 + o];
        }
    }
}

extern "C" void kernel_launch(void* const* d_in, const int* in_sizes, int n_in,
                              void* d_out, int out_size, void* d_ws, size_t ws_size,
                              hipStream_t stream) {
    const float* h     = (const float*)d_in[0];
    const float* wconn = (const float*)d_in[1];
    const float* ctx   = (const float*)d_in[2];
    const float* nid   = (const float*)d_in[3];
    const float* mw1   = (const float*)d_in[4];
    const float* mb1   = (const float*)d_in[5];
    const float* mw2   = (const float*)d_in[6];
    const float* mb2   = (const float*)d_in[7];
    const float* sw1   = (const float*)d_in[8];
    const float* sb1   = (const float*)d_in[9];
    const float* sw2   = (const float*)d_in[10];
    const float* sb2   = (const float*)d_in[11];
    const float* dw1   = (const float*)d_in[12];
    const float* db1   = (const float*)d_in[13];
    const float* dw2   = (const float*)d_in[14];
    const float* db2   = (const float*)d_in[15];
    const int* conn    = (const int*)d_in[16];
    const int* c2g     = (const int*)d_in[17];
    float* outf    = (float*)d_out;
    u16*   wb      = (u16*)d_ws;                        // bf16 weight copies (1 MB)
    float* partial = (float*)((char*)d_ws + 1048576);   // [2048][128] f32 (1 MB)

    cvt_w<<<512, 256, 0, stream>>>(mw1, mw2, sw1, sw2, wb);
    mg_main<<<2048, 64, 0, stream>>>(h, wconn, ctx, nid,
                                     wb,           mb1,
                                     wb + 196608,  mb2,
                                     wb + 262144,  sb1,
                                     wb + 458752,  sb2,
                                     conn, c2g, outf, partial);
    mg_mod<<<512, 256, 0, stream>>>(dw1, db1, dw2, db2, partial, outf);
}